// Round 4
// baseline (256.324 us; speedup 1.0000x reference)
//
#include <hip/hip_runtime.h>

#define SEQ   2000
#define TAPS  7
#define C4    32            // float4 per input channel row (128 floats)
#define ROW4  (TAPS * C4)   // 224 float4 per output row
#define BATCH 32
#define G     8             // output rows per block
#define BLK   256

typedef float f4 __attribute__((ext_vector_type(4)));

// Shifted-copy formulation. Output row (b,i) == x[b, i-6 .. i, :] flattened,
// so per output f4 index F (within batch): i = F/224, rem = F%224,
// source f4 index s4 = 32*i + rem - 192; value = s4 >= 0 ? x4[s4] : 0.
// Each block owns a contiguous 28 KB output span (8 rows); each wave store is
// one 1024 B contiguous segment walking the output linearly (fill-like).
__global__ __launch_bounds__(BLK) void conv_window_kernel(
    const float* __restrict__ x, float* __restrict__ out) {
    const int b  = blockIdx.y;
    const int F0 = blockIdx.x * (G * ROW4);   // block's first f4 within batch

    const f4* __restrict__ xb =
        reinterpret_cast<const f4*>(x) + (size_t)b * SEQ * C4;
    f4* __restrict__ ob =
        reinterpret_cast<f4*>(out) + (size_t)b * SEQ * ROW4 + F0;

#pragma unroll
    for (int k = 0; k < (G * ROW4) / BLK; ++k) {          // 7 iterations
        const int f   = F0 + k * BLK + threadIdx.x;       // flat output f4 idx
        const int i   = f / ROW4;                         // magic-div by 224
        const int rem = f - i * ROW4;
        const int s4  = i * C4 + rem - (TAPS - 1) * C4;   // shifted source idx
        f4 v = {0.f, 0.f, 0.f, 0.f};
        if (s4 >= 0) v = xb[s4];                          // predicated load
        ob[k * BLK + threadIdx.x] = v;                    // 1024 B/wave, linear
    }
}

extern "C" void kernel_launch(void* const* d_in, const int* in_sizes, int n_in,
                              void* d_out, int out_size, void* d_ws, size_t ws_size,
                              hipStream_t stream) {
    const float* x = (const float*)d_in[0];
    float* out = (float*)d_out;
    dim3 grid(SEQ / G, BATCH);   // 250 x 32 = 8000 blocks
    conv_window_kernel<<<grid, BLK, 0, stream>>>(x, out);
}

// Round 7
// 255.138 us; speedup vs baseline: 1.0046x; 1.0046x over previous
//
#include <hip/hip_runtime.h>

#define SEQ   2000
#define TAPS  7
#define C4    32            // float4 per input channel row (128 floats)
#define ROW4  (TAPS * C4)   // 224 float4 per output row
#define BATCH 32
#define G     8             // output rows per block
#define BLK   256

typedef float f4 __attribute__((ext_vector_type(4)));

// Shifted-copy formulation. Output row (b,i) == x[b, i-6 .. i, :] flattened:
// per output f4 index F (within batch): i = F/224, rem = F%224,
// source f4 index s4 = 32*i + rem - 192; value = s4 >= 0 ? x4[s4] : 0.
// Each block owns a contiguous 28 KB output span (8 rows); each wave store is
// one 1024 B contiguous segment walking the output linearly (fill-like).
// NT stores: the 229 MB output stream is never re-read -> bypass L2, keep it
// for the 7x-reused input.
__global__ __launch_bounds__(BLK) void conv_window_kernel(
    const float* __restrict__ x, float* __restrict__ out) {
    const int b  = blockIdx.y;
    const int F0 = blockIdx.x * (G * ROW4);   // block's first f4 within batch

    const f4* __restrict__ xb =
        reinterpret_cast<const f4*>(x) + (size_t)b * SEQ * C4;
    f4* __restrict__ ob =
        reinterpret_cast<f4*>(out) + (size_t)b * SEQ * ROW4 + F0;

#pragma unroll
    for (int k = 0; k < (G * ROW4) / BLK; ++k) {          // 7 iterations
        const int f   = F0 + k * BLK + threadIdx.x;       // flat output f4 idx
        const int i   = f / ROW4;                         // magic-div by 224
        const int rem = f - i * ROW4;
        const int s4  = i * C4 + rem - (TAPS - 1) * C4;   // shifted source idx
        f4 v = {0.f, 0.f, 0.f, 0.f};
        if (s4 >= 0) v = xb[s4];                          // predicated load
        __builtin_nontemporal_store(v, &ob[k * BLK + threadIdx.x]);
    }
}

extern "C" void kernel_launch(void* const* d_in, const int* in_sizes, int n_in,
                              void* d_out, int out_size, void* d_ws, size_t ws_size,
                              hipStream_t stream) {
    const float* x = (const float*)d_in[0];
    float* out = (float*)d_out;
    dim3 grid(SEQ / G, BATCH);   // 250 x 32 = 8000 blocks
    conv_window_kernel<<<grid, BLK, 0, stream>>>(x, out);
}